// Round 3
// baseline (1069.539 us; speedup 1.0000x reference)
//
#include <hip/hip_runtime.h>
#include <hip/hip_bf16.h>

#define VOCAB 32000
#define HID   256
#define BATCH 32
#define SEQ   128
#define MROWS (BATCH * SEQ)  // 4096
#define NCB   250            // VOCAB / 128 column blocks

typedef _Float16 f16;
typedef _Float16 f16x4 __attribute__((ext_vector_type(4)));
typedef _Float16 f16x8 __attribute__((ext_vector_type(8)));
typedef float    f32x4 __attribute__((ext_vector_type(4)));

#define GLOAD_LDS16(gptr, lptr)                                                       \
  __builtin_amdgcn_global_load_lds(                                                   \
      (const __attribute__((address_space(1))) unsigned int*)(gptr),                  \
      (__attribute__((address_space(3))) unsigned int*)(lptr), 16, 0, 0)

// ---------------------------------------------------------------------------
// 1) embedding lookup + mask:  x[b,t,:] = (t < len[b]) ? emb[tok] : 0
// ---------------------------------------------------------------------------
__global__ __launch_bounds__(256) void embed_kernel(
    const int* __restrict__ tokens, const int* __restrict__ lengths,
    const float* __restrict__ emb, float* __restrict__ x) {
  int row = blockIdx.x;            // b*SEQ + t
  int b = row >> 7, t = row & 127;
  int tok = tokens[row];
  float v = (t < lengths[b]) ? emb[(size_t)tok * HID + threadIdx.x] : 0.f;
  x[(size_t)row * HID + threadIdx.x] = v;
}

// ---------------------------------------------------------------------------
// 2) fp32 -> fp16 cast (float4 -> 4 halfs per thread)
// ---------------------------------------------------------------------------
__global__ __launch_bounds__(256) void cast_kernel(
    const float* __restrict__ in, f16* __restrict__ out, int n4) {
  int idx = blockIdx.x * 256 + threadIdx.x;
  if (idx >= n4) return;
  float4 v = ((const float4*)in)[idx];
  f16x4 o = {(f16)v.x, (f16)v.y, (f16)v.z, (f16)v.w};
  ((f16x4*)out)[idx] = o;
}

// ---------------------------------------------------------------------------
// 3) X = In @ W^T + bias   (In: [4096][256], W: [256][256] row-major, fp32)
// ---------------------------------------------------------------------------
__global__ __launch_bounds__(256) void xprep_kernel(
    const float* __restrict__ In, const float* __restrict__ W,
    const float* __restrict__ bias, float* __restrict__ Out) {
  __shared__ float sIn[16 * 256];
  int tid = threadIdx.x;
  int rb = blockIdx.x * 16;
  const float4* g = (const float4*)(In + (size_t)rb * 256);
  float4* s4 = (float4*)sIn;
#pragma unroll
  for (int q = 0; q < 4; ++q) s4[tid + q * 256] = g[tid + q * 256];
  __syncthreads();
  int i = tid;
  float acc[16];
#pragma unroll
  for (int r = 0; r < 16; ++r) acc[r] = 0.f;
  const float4* w4 = (const float4*)(W + (size_t)i * 256);
#pragma unroll 4
  for (int j = 0; j < 64; ++j) {
    float4 wv = w4[j];
#pragma unroll
    for (int r = 0; r < 16; ++r) {
      float4 sv = ((const float4*)(sIn + r * 256))[j];
      acc[r] += sv.x * wv.x + sv.y * wv.y + sv.z * wv.z + sv.w * wv.w;
    }
  }
  float bi = bias[i];
#pragma unroll
  for (int r = 0; r < 16; ++r) Out[(size_t)(rb + r) * 256 + i] = acc[r] + bi;
}

// ---------------------------------------------------------------------------
// 4) recurrence: h_t = tanh(X_t + h_{t-1} @ Wh^T); output masked, carry unmasked
// ---------------------------------------------------------------------------
__global__ __launch_bounds__(512) void rnn_kernel(
    const float* __restrict__ X, const float* __restrict__ Wh,
    const int* __restrict__ lengths, float* __restrict__ Hout) {
  int b = blockIdx.x;
  int tid = threadIdx.x;
  int i = tid & 255;
  int half = tid >> 8;  // wave-uniform
  float w[128];
  {
    const float4* wr = (const float4*)(Wh + (size_t)i * 256 + half * 128);
#pragma unroll
    for (int q = 0; q < 32; ++q) {
      float4 v = wr[q];
      w[4 * q + 0] = v.x; w[4 * q + 1] = v.y;
      w[4 * q + 2] = v.z; w[4 * q + 3] = v.w;
    }
  }
  __shared__ float sh[256];
  __shared__ float sp[256];
  if (tid < 256) sh[tid] = 0.f;
  int len = lengths[b];
  const float* Xb = X + (size_t)b * SEQ * HID;
  float* Hb = Hout + (size_t)b * SEQ * HID;
  __syncthreads();
  float xnext = (half == 0) ? Xb[i] : 0.f;
  for (int t = 0; t < SEQ; ++t) {
    float a0 = 0.f, a1 = 0.f, a2 = 0.f, a3 = 0.f;
    const float4* hp = (const float4*)(sh + half * 128);
#pragma unroll
    for (int q = 0; q < 32; ++q) {
      float4 hv = hp[q];
      a0 += hv.x * w[4 * q + 0];
      a1 += hv.y * w[4 * q + 1];
      a2 += hv.z * w[4 * q + 2];
      a3 += hv.w * w[4 * q + 3];
    }
    float acc = (a0 + a1) + (a2 + a3);
    if (half) sp[i] = acc;
    __syncthreads();
    if (!half) {
      float h = tanhf(xnext + acc + sp[i]);
      Hb[(size_t)t * HID + i] = (t < len) ? h : 0.f;  // masked output
      sh[i] = h;                                      // unmasked carry
      if (t + 1 < SEQ) xnext = Xb[(size_t)(t + 1) * HID + i];
    }
    __syncthreads();
  }
}

// ---------------------------------------------------------------------------
// 5) Two-pass fused GEMM+softmax, double-buffered prefetch K-loop.
//    - 2-phase pipeline: STAGE(next) issued BEFORE compute(cur); one barrier
//      per K-step; global-load latency overlaps ds_read+MFMA (T3-minimum).
//    - XCD-chunked block remap: each XCD owns ~32 consecutive col-blocks ->
//      B tile (2MB) + A (2MB) fit that XCD's 4MB L2.
//    - length-aware fragment skip retained (row tile == one batch element).
// ---------------------------------------------------------------------------
template <int WRITE_PROBS>
__global__ __launch_bounds__(256) void gemm_kernel(
    const f16* __restrict__ A,   // [4096][256] masked h2
    const f16* __restrict__ Bm,  // [32000][256] emb
    float* __restrict__ C,       // [4096][32000] probs (pass 2 only)
    float* __restrict__ PM,      // [4096][250] partial row max (pass 1)
    float* __restrict__ PL,      // [4096][250] partial sum exp (pass 1)
    const float* __restrict__ Mrow,  // [4096] row max (pass 2)
    const float* __restrict__ Inv,   // [4096] 1/denominator (pass 2)
    const int* __restrict__ lengths) {
  __shared__ __align__(16) f16 sAbuf[2][128 * 64];  // 32 KB
  __shared__ __align__(16) f16 sBbuf[2][128 * 64];  // 32 KB  (total = 64 KB)
  const int tid = threadIdx.x;
  const int wave = tid >> 6;
  const int lane = tid & 63;

  // XCD-chunked remap (8000 blocks, 1000 per XCD; round-robin dispatch)
  const int flat = blockIdx.x + 32 * blockIdx.y;
  const int work = (flat & 7) * 1000 + (flat >> 3);
  const int bx = work & 31;   // row-block == batch element
  const int by = work >> 5;   // col-block
  const int row0 = bx * 128;
  const int col0 = by * 128;

  const int len = lengths[bx];         // block-uniform
  const int lenc = (len + 15) & ~15;   // rows needed, frag-rounded

  f32x4 acc[4][4];
#pragma unroll
  for (int a = 0; a < 4; ++a)
#pragma unroll
    for (int b = 0; b < 4; ++b) acc[a][b] = (f32x4){0.f, 0.f, 0.f, 0.f};

  const int lr = lane >> 3;  // row within 8-row group
  const int ls = lane & 7;   // LDS 16B slot within row
  const int wm = wave & 1, wn = wave >> 1;

#define STAGE(buf, koo)                                                        \
  {                                                                            \
    _Pragma("unroll") for (int ii = 0; ii < 4; ++ii) {                         \
      int ar = wave * 32 + ii * 8;                                             \
      int r = ar + lr;                                                         \
      int c = ls ^ (r & 7);                                                    \
      if (ar < lenc) {                                                         \
        const f16* ga = A + (size_t)(row0 + r) * 256 + (koo) * 64 + c * 8;     \
        GLOAD_LDS16(ga, sAbuf[buf] + ar * 64);                                 \
      }                                                                        \
      const f16* gb = Bm + (size_t)(col0 + r) * 256 + (koo) * 64 + c * 8;      \
      GLOAD_LDS16(gb, sBbuf[buf] + ar * 64);                                   \
    }                                                                          \
  }

  STAGE(0, 0);
  __syncthreads();  // prologue drain (implicit vmcnt(0))

#pragma unroll
  for (int ko = 0; ko < 4; ++ko) {
    const int cur = ko & 1;
    if (ko < 3) STAGE(cur ^ 1, ko + 1);  // prefetch overlaps compute below
#pragma unroll
    for (int kk = 0; kk < 2; ++kk) {
      const int cA = kk * 4 + (lane >> 4);
      f16x8 bf[4];
#pragma unroll
      for (int f = 0; f < 4; ++f) {
        int n = wn * 64 + f * 16 + (lane & 15);
        bf[f] = *(const f16x8*)(sBbuf[cur] + n * 64 + (cA ^ (n & 7)) * 8);
      }
#pragma unroll
      for (int fm = 0; fm < 4; ++fm) {
        const int g = fm * 2 + wm;        // interleaved row-frag index
        if (g * 16 < len) {               // wave-uniform guard
          int m = g * 16 + (lane & 15);
          f16x8 af = *(const f16x8*)(sAbuf[cur] + m * 64 + (cA ^ (m & 7)) * 8);
#pragma unroll
          for (int fn = 0; fn < 4; ++fn)
            acc[fm][fn] = __builtin_amdgcn_mfma_f32_16x16x32_f16(
                af, bf[fn], acc[fm][fn], 0, 0, 0);
        }
      }
    }
    __syncthreads();  // next buffer ready + old buffer readers done
  }
#undef STAGE

  const int lq = lane >> 4;
  const int lc = lane & 15;

  if (WRITE_PROBS) {
    // --- pass 2: probs = exp(acc - m) * inv, masked rows -> 0 ---
    // C/D layout: col=lane&15, row=(lane>>4)*4+reg
    float* sM = (float*)sAbuf;  // staging buffers dead after final barrier
    float* sI = sM + 128;
    if (tid < 128) {
      sM[tid] = Mrow[row0 + tid];
      sI[tid] = Inv[row0 + tid];
    }
    __syncthreads();
#pragma unroll
    for (int fm = 0; fm < 4; ++fm)
#pragma unroll
      for (int fn = 0; fn < 4; ++fn)
#pragma unroll
        for (int rr = 0; rr < 4; ++rr) {
          int t = (fm * 2 + wm) * 16 + lq * 4 + rr;  // t within batch
          int col = col0 + wn * 64 + fn * 16 + lc;
          float v =
              (t < len) ? __expf(acc[fm][fn][rr] - sM[t]) * sI[t] : 0.f;
          C[(size_t)(row0 + t) * VOCAB + col] = v;
        }
  } else {
    // --- pass 1: per-block online-softmax partials; reuse staging LDS ---
    float* rm = (float*)sAbuf;     // [2][128]  per-wn per-row max
    float* rs = rm + 256;          // [2][128]  per-wn per-row sum exp
#pragma unroll
    for (int fm = 0; fm < 4; ++fm) {
      const int g = fm * 2 + wm;
      const bool active = (g * 16 < len);  // wave-uniform
#pragma unroll
      for (int rr = 0; rr < 4; ++rr) {
        int r = g * 16 + lq * 4 + rr;
        if (active) {
          float mx = fmaxf(fmaxf(acc[fm][0][rr], acc[fm][1][rr]),
                           fmaxf(acc[fm][2][rr], acc[fm][3][rr]));
#pragma unroll
          for (int off = 1; off < 16; off <<= 1)
            mx = fmaxf(mx, __shfl_xor(mx, off, 64));
          float sum = __expf(acc[fm][0][rr] - mx) +
                      __expf(acc[fm][1][rr] - mx) +
                      __expf(acc[fm][2][rr] - mx) +
                      __expf(acc[fm][3][rr] - mx);
#pragma unroll
          for (int off = 1; off < 16; off <<= 1)
            sum += __shfl_xor(sum, off, 64);
          if (lc == 0) {
            rm[wn * 128 + r] = mx;
            rs[wn * 128 + r] = sum;
          }
        } else if (lc == 0) {  // padded rows: benign partials (unused)
          rm[wn * 128 + r] = 0.f;
          rs[wn * 128 + r] = 0.f;
        }
      }
    }
    __syncthreads();
    if (tid < 128) {
      float m0 = rm[tid], m1 = rm[128 + tid];
      float M = fmaxf(m0, m1);
      float L = rs[tid] * __expf(m0 - M) + rs[128 + tid] * __expf(m1 - M);
      PM[(size_t)(row0 + tid) * NCB + by] = M;
      PL[(size_t)(row0 + tid) * NCB + by] = L;
    }
  }
}

// ---------------------------------------------------------------------------
// 6) combine 250 partials per row -> m[row], inv[row]. One wave per row.
// ---------------------------------------------------------------------------
__global__ __launch_bounds__(256) void combine_kernel(
    const float* __restrict__ PM, const float* __restrict__ PL,
    float* __restrict__ Mrow, float* __restrict__ Inv) {
  int row = blockIdx.x * 4 + (threadIdx.x >> 6);
  int lane = threadIdx.x & 63;
  const float* pm = PM + (size_t)row * NCB;
  const float* pl = PL + (size_t)row * NCB;
  float M = -3.4e38f;
  for (int i = lane; i < NCB; i += 64) M = fmaxf(M, pm[i]);
#pragma unroll
  for (int off = 1; off < 64; off <<= 1) M = fmaxf(M, __shfl_xor(M, off, 64));
  float L = 0.f;
  for (int i = lane; i < NCB; i += 64) L += pl[i] * __expf(pm[i] - M);
#pragma unroll
  for (int off = 1; off < 64; off <<= 1) L += __shfl_xor(L, off, 64);
  if (lane == 0) {
    Mrow[row] = M;
    Inv[row] = 1.f / L;
  }
}

// ---------------------------------------------------------------------------
extern "C" void kernel_launch(void* const* d_in, const int* in_sizes, int n_in,
                              void* d_out, int out_size, void* d_ws,
                              size_t ws_size, hipStream_t stream) {
  const int* tokens = (const int*)d_in[0];
  const int* lengths = (const int*)d_in[1];
  const float* emb = (const float*)d_in[2];
  const float* Wx1 = (const float*)d_in[3];
  const float* Wh1 = (const float*)d_in[4];
  const float* b1 = (const float*)d_in[5];
  const float* Wx2 = (const float*)d_in[6];
  const float* Wh2 = (const float*)d_in[7];
  const float* b2 = (const float*)d_in[8];

  float* probs = (float*)d_out;
  float* h2out = probs + (size_t)MROWS * VOCAB;  // [4096][256] masked h2

  float* ws = (float*)d_ws;
  float* x = ws;                               // 1,048,576 f
  float* X = ws + 1048576;                     // 1,048,576 f (reused layer 2)
  float* h1 = ws + 2097152;                    // 1,048,576 f
  f16* embh = (f16*)(ws + 3145728);            // 8,192,000 halfs = 4,096,000 f
  f16* h2h = (f16*)(ws + 3145728 + 4096000);   // 1,048,576 halfs = 524,288 f
  float* PM = ws + 7766016;                    // 1,024,000 f
  float* PL = ws + 8790016;                    // 1,024,000 f
  float* Mrow = ws + 9814016;                  // 4096 f
  float* Inv = ws + 9818112;                   // 4096 f

  embed_kernel<<<MROWS, 256, 0, stream>>>(tokens, lengths, emb, x);
  cast_kernel<<<8000, 256, 0, stream>>>(emb, embh, VOCAB * HID / 4);

  xprep_kernel<<<256, 256, 0, stream>>>(x, Wx1, b1, X);
  rnn_kernel<<<BATCH, 512, 0, stream>>>(X, Wh1, lengths, h1);
  xprep_kernel<<<256, 256, 0, stream>>>(h1, Wx2, b2, X);
  rnn_kernel<<<BATCH, 512, 0, stream>>>(X, Wh2, lengths, h2out);

  cast_kernel<<<1024, 256, 0, stream>>>(h2out, h2h, MROWS * HID / 4);

  dim3 gg(32, NCB);
  // pass 1: partials only (no 524MB logits write), length-skipped
  gemm_kernel<0><<<gg, 256, 0, stream>>>(h2h, embh, nullptr, PM, PL,
                                         nullptr, nullptr, lengths);
  combine_kernel<<<MROWS / 4, 256, 0, stream>>>(PM, PL, Mrow, Inv);
  // pass 2: recompute + fused exp/scale/mask, write probs directly
  gemm_kernel<1><<<gg, 256, 0, stream>>>(h2h, embh, probs, nullptr, nullptr,
                                         Mrow, Inv, lengths);
}

// Round 4
// 1055.914 us; speedup vs baseline: 1.0129x; 1.0129x over previous
//
#include <hip/hip_runtime.h>
#include <hip/hip_bf16.h>

#define VOCAB 32000
#define HID   256
#define BATCH 32
#define SEQ   128
#define MROWS (BATCH * SEQ)  // 4096
#define NCB   250            // VOCAB / 128 column blocks

typedef _Float16 f16;
typedef _Float16 f16x4 __attribute__((ext_vector_type(4)));
typedef _Float16 f16x8 __attribute__((ext_vector_type(8)));
typedef float    f32x4 __attribute__((ext_vector_type(4)));

#define GLOAD_LDS16(gptr, lptr)                                                       \
  __builtin_amdgcn_global_load_lds(                                                   \
      (const __attribute__((address_space(1))) unsigned int*)(gptr),                  \
      (__attribute__((address_space(3))) unsigned int*)(lptr), 16, 0, 0)

// ---------------------------------------------------------------------------
// 1) fp32 -> fp16 cast (float4 -> 4 halfs per thread)  [emb only now]
// ---------------------------------------------------------------------------
__global__ __launch_bounds__(256) void cast_kernel(
    const float* __restrict__ in, f16* __restrict__ out, int n4) {
  int idx = blockIdx.x * 256 + threadIdx.x;
  if (idx >= n4) return;
  float4 v = ((const float4*)in)[idx];
  f16x4 o = {(f16)v.x, (f16)v.y, (f16)v.z, (f16)v.w};
  ((f16x4*)out)[idx] = o;
}

// ---------------------------------------------------------------------------
// 2) X = In @ W^T + bias.  GATHER=1: In rows come from emb[tokens[row]]
//    masked by length (fuses the old embed_kernel); GATHER=0: linear In.
// ---------------------------------------------------------------------------
template <int GATHER>
__global__ __launch_bounds__(256) void xprep_kernel(
    const float* __restrict__ In, const int* __restrict__ tokens,
    const int* __restrict__ lengths, const float* __restrict__ emb,
    const float* __restrict__ W, const float* __restrict__ bias,
    float* __restrict__ Out) {
  __shared__ float sIn[16 * 256];
  int tid = threadIdx.x;
  int rb = blockIdx.x * 16;
  float4* s4 = (float4*)sIn;
#pragma unroll
  for (int q = 0; q < 4; ++q) {
    int f = tid + q * 256;  // float4 index within 16x256 tile
    float4 v;
    if (GATHER) {
      int row = f >> 6;     // 0..15
      int c4 = f & 63;
      int gr = rb + row;    // global row = b*SEQ + t
      int bb = gr >> 7, t = gr & 127;
      if (t < lengths[bb]) {
        int tok = tokens[gr];
        v = ((const float4*)(emb + (size_t)tok * 256))[c4];
      } else {
        v = make_float4(0.f, 0.f, 0.f, 0.f);
      }
    } else {
      v = ((const float4*)(In + (size_t)rb * 256))[f];
    }
    s4[f] = v;
  }
  __syncthreads();
  int i = tid;
  float acc[16];
#pragma unroll
  for (int r = 0; r < 16; ++r) acc[r] = 0.f;
  const float4* w4 = (const float4*)(W + (size_t)i * 256);
#pragma unroll 4
  for (int j = 0; j < 64; ++j) {
    float4 wv = w4[j];
#pragma unroll
    for (int r = 0; r < 16; ++r) {
      float4 sv = ((const float4*)(sIn + r * 256))[j];
      acc[r] += sv.x * wv.x + sv.y * wv.y + sv.z * wv.z + sv.w * wv.w;
    }
  }
  float bi = bias[i];
#pragma unroll
  for (int r = 0; r < 16; ++r) Out[(size_t)(rb + r) * 256 + i] = acc[r] + bi;
}

// ---------------------------------------------------------------------------
// 3) recurrence: h_t = tanh(X_t + h_{t-1} @ Wh^T); output masked, carry
//    unmasked.  Wave-level K-split: each wave owns 32 outputs; lanes l and
//    l^32 hold the two K-halves of output o = wave*32 + (l&31); partials
//    combined by one __shfl_xor (no LDS round-trip).  sh double-buffered
//    -> ONE barrier per step (was 2).  Fast tanh via __expf.
//    H16: optional f16 mirror of the masked output (fuses the h2 cast).
// ---------------------------------------------------------------------------
__global__ __launch_bounds__(512) void rnn_kernel(
    const float* __restrict__ X, const float* __restrict__ Wh,
    const int* __restrict__ lengths, float* __restrict__ Hout,
    f16* __restrict__ H16) {
  int b = blockIdx.x;
  int tid = threadIdx.x;
  int wave = tid >> 6;
  int lane = tid & 63;
  int o = wave * 32 + (lane & 31);  // output index this lane serves
  int kh = lane >> 5;               // K-half (0/1), wave-uniform? no: per-lane
  float w[128];
  {
    const float4* wr = (const float4*)(Wh + (size_t)o * 256 + kh * 128);
#pragma unroll
    for (int q = 0; q < 32; ++q) {
      float4 v = wr[q];
      w[4 * q + 0] = v.x; w[4 * q + 1] = v.y;
      w[4 * q + 2] = v.z; w[4 * q + 3] = v.w;
    }
  }
  __shared__ float sh[2][256];
  if (tid < 256) sh[0][tid] = 0.f;
  int len = lengths[b];
  const float* Xb = X + (size_t)b * SEQ * HID;
  float* Hb = Hout + (size_t)b * SEQ * HID;
  f16* H16b = H16 + (size_t)b * SEQ * HID;  // only deref'd if H16 != nullptr
  __syncthreads();
  float xnext = (kh == 0) ? Xb[o] : 0.f;
  for (int t = 0; t < SEQ; ++t) {
    const int cur = t & 1;
    float a0 = 0.f, a1 = 0.f, a2 = 0.f, a3 = 0.f;
    const float4* hp = (const float4*)(sh[cur] + kh * 128);
#pragma unroll
    for (int q = 0; q < 32; ++q) {
      float4 hv = hp[q];
      a0 += hv.x * w[4 * q + 0];
      a1 += hv.y * w[4 * q + 1];
      a2 += hv.z * w[4 * q + 2];
      a3 += hv.w * w[4 * q + 3];
    }
    float acc = (a0 + a1) + (a2 + a3);
    acc += __shfl_xor(acc, 32, 64);  // combine the two K-halves
    if (kh == 0) {
      float z = xnext + acc;
      float e = __expf(2.f * z);           // fast tanh: 1 - 2/(e^{2z}+1)
      float h = 1.f - 2.f / (e + 1.f);
      float hm = (t < len) ? h : 0.f;
      Hb[(size_t)t * HID + o] = hm;        // masked output
      if (H16) H16b[(size_t)t * HID + o] = (f16)hm;
      sh[cur ^ 1][o] = h;                  // unmasked carry
      if (t + 1 < SEQ) xnext = Xb[(size_t)(t + 1) * HID + o];
    }
    __syncthreads();  // write(next buf) -> read ordering; reads of cur done
  }
}

// ---------------------------------------------------------------------------
// 4) Two-pass fused GEMM+softmax, double-buffered prefetch K-loop.
//    Pass 2 uses nontemporal stores for the 524MB probs stream (keep A/B in
//    L2).  XCD-chunked remap + length-aware fragment skip retained.
// ---------------------------------------------------------------------------
template <int WRITE_PROBS>
__global__ __launch_bounds__(256) void gemm_kernel(
    const f16* __restrict__ A,   // [4096][256] masked h2
    const f16* __restrict__ Bm,  // [32000][256] emb
    float* __restrict__ C,       // [4096][32000] probs (pass 2 only)
    float* __restrict__ PM,      // [4096][250] partial row max (pass 1)
    float* __restrict__ PL,      // [4096][250] partial sum exp (pass 1)
    const float* __restrict__ Mrow,  // [4096] row max (pass 2)
    const float* __restrict__ Inv,   // [4096] 1/denominator (pass 2)
    const int* __restrict__ lengths) {
  __shared__ __align__(16) f16 sAbuf[2][128 * 64];  // 32 KB
  __shared__ __align__(16) f16 sBbuf[2][128 * 64];  // 32 KB  (total = 64 KB)
  const int tid = threadIdx.x;
  const int wave = tid >> 6;
  const int lane = tid & 63;

  // XCD-chunked remap (8000 blocks, 1000 per XCD; round-robin dispatch)
  const int flat = blockIdx.x + 32 * blockIdx.y;
  const int work = (flat & 7) * 1000 + (flat >> 3);
  const int bx = work & 31;   // row-block == batch element
  const int by = work >> 5;   // col-block
  const int row0 = bx * 128;
  const int col0 = by * 128;

  const int len = lengths[bx];         // block-uniform
  const int lenc = (len + 15) & ~15;   // rows needed, frag-rounded

  f32x4 acc[4][4];
#pragma unroll
  for (int a = 0; a < 4; ++a)
#pragma unroll
    for (int b = 0; b < 4; ++b) acc[a][b] = (f32x4){0.f, 0.f, 0.f, 0.f};

  const int lr = lane >> 3;  // row within 8-row group
  const int ls = lane & 7;   // LDS 16B slot within row
  const int wm = wave & 1, wn = wave >> 1;

#define STAGE(buf, koo)                                                        \
  {                                                                            \
    _Pragma("unroll") for (int ii = 0; ii < 4; ++ii) {                         \
      int ar = wave * 32 + ii * 8;                                             \
      int r = ar + lr;                                                         \
      int c = ls ^ (r & 7);                                                    \
      if (ar < lenc) {                                                         \
        const f16* ga = A + (size_t)(row0 + r) * 256 + (koo) * 64 + c * 8;     \
        GLOAD_LDS16(ga, sAbuf[buf] + ar * 64);                                 \
      }                                                                        \
      const f16* gb = Bm + (size_t)(col0 + r) * 256 + (koo) * 64 + c * 8;      \
      GLOAD_LDS16(gb, sBbuf[buf] + ar * 64);                                   \
    }                                                                          \
  }

  STAGE(0, 0);
  __syncthreads();  // prologue drain (implicit vmcnt(0))

#pragma unroll
  for (int ko = 0; ko < 4; ++ko) {
    const int cur = ko & 1;
    if (ko < 3) STAGE(cur ^ 1, ko + 1);  // prefetch overlaps compute below
#pragma unroll
    for (int kk = 0; kk < 2; ++kk) {
      const int cA = kk * 4 + (lane >> 4);
      f16x8 bf[4];
#pragma unroll
      for (int f = 0; f < 4; ++f) {
        int n = wn * 64 + f * 16 + (lane & 15);
        bf[f] = *(const f16x8*)(sBbuf[cur] + n * 64 + (cA ^ (n & 7)) * 8);
      }
#pragma unroll
      for (int fm = 0; fm < 4; ++fm) {
        const int g = fm * 2 + wm;        // interleaved row-frag index
        if (g * 16 < len) {               // wave-uniform guard
          int m = g * 16 + (lane & 15);
          f16x8 af = *(const f16x8*)(sAbuf[cur] + m * 64 + (cA ^ (m & 7)) * 8);
#pragma unroll
          for (int fn = 0; fn < 4; ++fn)
            acc[fm][fn] = __builtin_amdgcn_mfma_f32_16x16x32_f16(
                af, bf[fn], acc[fm][fn], 0, 0, 0);
        }
      }
    }
    __syncthreads();  // next buffer ready + old buffer readers done
  }
#undef STAGE

  const int lq = lane >> 4;
  const int lc = lane & 15;

  if (WRITE_PROBS) {
    // --- pass 2: probs = exp(acc - m) * inv, masked rows -> 0 ---
    // C/D layout: col=lane&15, row=(lane>>4)*4+reg.  Nontemporal stores.
    float* sM = (float*)sAbuf;  // staging buffers dead after final barrier
    float* sI = sM + 128;
    if (tid < 128) {
      sM[tid] = Mrow[row0 + tid];
      sI[tid] = Inv[row0 + tid];
    }
    __syncthreads();
#pragma unroll
    for (int fm = 0; fm < 4; ++fm)
#pragma unroll
      for (int fn = 0; fn < 4; ++fn)
#pragma unroll
        for (int rr = 0; rr < 4; ++rr) {
          int t = (fm * 2 + wm) * 16 + lq * 4 + rr;  // t within batch
          int col = col0 + wn * 64 + fn * 16 + lc;
          float v =
              (t < len) ? __expf(acc[fm][fn][rr] - sM[t]) * sI[t] : 0.f;
          __builtin_nontemporal_store(v, &C[(size_t)(row0 + t) * VOCAB + col]);
        }
  } else {
    // --- pass 1: per-block online-softmax partials; reuse staging LDS ---
    float* rm = (float*)sAbuf;     // [2][128]  per-wn per-row max
    float* rs = rm + 256;          // [2][128]  per-wn per-row sum exp
#pragma unroll
    for (int fm = 0; fm < 4; ++fm) {
      const int g = fm * 2 + wm;
      const bool active = (g * 16 < len);  // wave-uniform
#pragma unroll
      for (int rr = 0; rr < 4; ++rr) {
        int r = g * 16 + lq * 4 + rr;
        if (active) {
          float mx = fmaxf(fmaxf(acc[fm][0][rr], acc[fm][1][rr]),
                           fmaxf(acc[fm][2][rr], acc[fm][3][rr]));
#pragma unroll
          for (int off = 1; off < 16; off <<= 1)
            mx = fmaxf(mx, __shfl_xor(mx, off, 64));
          float sum = __expf(acc[fm][0][rr] - mx) +
                      __expf(acc[fm][1][rr] - mx) +
                      __expf(acc[fm][2][rr] - mx) +
                      __expf(acc[fm][3][rr] - mx);
#pragma unroll
          for (int off = 1; off < 16; off <<= 1)
            sum += __shfl_xor(sum, off, 64);
          if (lc == 0) {
            rm[wn * 128 + r] = mx;
            rs[wn * 128 + r] = sum;
          }
        } else if (lc == 0) {  // padded rows: benign partials (unused)
          rm[wn * 128 + r] = 0.f;
          rs[wn * 128 + r] = 0.f;
        }
      }
    }
    __syncthreads();
    if (tid < 128) {
      float m0 = rm[tid], m1 = rm[128 + tid];
      float M = fmaxf(m0, m1);
      float L = rs[tid] * __expf(m0 - M) + rs[128 + tid] * __expf(m1 - M);
      PM[(size_t)(row0 + tid) * NCB + by] = M;
      PL[(size_t)(row0 + tid) * NCB + by] = L;
    }
  }
}

// ---------------------------------------------------------------------------
// 5) combine 250 partials per row -> m[row], inv[row]. One wave per row.
// ---------------------------------------------------------------------------
__global__ __launch_bounds__(256) void combine_kernel(
    const float* __restrict__ PM, const float* __restrict__ PL,
    float* __restrict__ Mrow, float* __restrict__ Inv) {
  int row = blockIdx.x * 4 + (threadIdx.x >> 6);
  int lane = threadIdx.x & 63;
  const float* pm = PM + (size_t)row * NCB;
  const float* pl = PL + (size_t)row * NCB;
  float M = -3.4e38f;
  for (int i = lane; i < NCB; i += 64) M = fmaxf(M, pm[i]);
#pragma unroll
  for (int off = 1; off < 64; off <<= 1) M = fmaxf(M, __shfl_xor(M, off, 64));
  float L = 0.f;
  for (int i = lane; i < NCB; i += 64) L += pl[i] * __expf(pm[i] - M);
#pragma unroll
  for (int off = 1; off < 64; off <<= 1) L += __shfl_xor(L, off, 64);
  if (lane == 0) {
    Mrow[row] = M;
    Inv[row] = 1.f / L;
  }
}

// ---------------------------------------------------------------------------
extern "C" void kernel_launch(void* const* d_in, const int* in_sizes, int n_in,
                              void* d_out, int out_size, void* d_ws,
                              size_t ws_size, hipStream_t stream) {
  const int* tokens = (const int*)d_in[0];
  const int* lengths = (const int*)d_in[1];
  const float* emb = (const float*)d_in[2];
  const float* Wx1 = (const float*)d_in[3];
  const float* Wh1 = (const float*)d_in[4];
  const float* b1 = (const float*)d_in[5];
  const float* Wx2 = (const float*)d_in[6];
  const float* Wh2 = (const float*)d_in[7];
  const float* b2 = (const float*)d_in[8];

  float* probs = (float*)d_out;
  float* h2out = probs + (size_t)MROWS * VOCAB;  // [4096][256] masked h2

  float* ws = (float*)d_ws;
  float* X = ws + 1048576;                     // 1,048,576 f (reused layer 2)
  float* h1 = ws + 2097152;                    // 1,048,576 f
  f16* embh = (f16*)(ws + 3145728);            // 8,192,000 halfs = 4,096,000 f
  f16* h2h = (f16*)(ws + 3145728 + 4096000);   // 1,048,576 halfs = 524,288 f
  float* PM = ws + 7766016;                    // 1,024,000 f
  float* PL = ws + 8790016;                    // 1,024,000 f
  float* Mrow = ws + 9814016;                  // 4096 f
  float* Inv = ws + 9818112;                   // 4096 f

  cast_kernel<<<8000, 256, 0, stream>>>(emb, embh, VOCAB * HID / 4);

  // layer 1: X1 = masked-emb-gather @ Wx1^T + b1 (embed fused into staging)
  xprep_kernel<1><<<256, 256, 0, stream>>>(nullptr, tokens, lengths, emb,
                                           Wx1, b1, X);
  rnn_kernel<<<BATCH, 512, 0, stream>>>(X, Wh1, lengths, h1, nullptr);
  xprep_kernel<0><<<256, 256, 0, stream>>>(h1, nullptr, nullptr, nullptr,
                                           Wx2, b2, X);
  // layer 2: writes f32 h2out AND f16 h2h (cast fused)
  rnn_kernel<<<BATCH, 512, 0, stream>>>(X, Wh2, lengths, h2out, h2h);

  dim3 gg(32, NCB);
  // pass 1: partials only (no 524MB logits write), length-skipped
  gemm_kernel<0><<<gg, 256, 0, stream>>>(h2h, embh, nullptr, PM, PL,
                                         nullptr, nullptr, lengths);
  combine_kernel<<<MROWS / 4, 256, 0, stream>>>(PM, PL, Mrow, Inv);
  // pass 2: recompute + fused exp/scale/mask, nontemporal probs stores
  gemm_kernel<1><<<gg, 256, 0, stream>>>(h2h, embh, probs, nullptr, nullptr,
                                         Mrow, Inv, lengths);
}